// Round 1
// baseline (229.163 us; speedup 1.0000x reference)
//
#include <hip/hip_runtime.h>

#define NQ     6
#define DIM    64
#define OH     63
#define HH     128
#define CIN    4
#define NB     128
#define SPT    8      // samples per tile per wave

// ---------------------------------------------------------------------------
// Kernel A: build the 64x64 circuit unitary, stored transposed:
//   Ut[j*64 + i] = U[i][j]   (float2 = {re, im})
// One block per basis column j; 64 lanes = 64 amplitudes.
// Qubit w lives at bit position (5 - w) of the amplitude index.
// ---------------------------------------------------------------------------
__global__ __launch_bounds__(64) void build_u(const float* __restrict__ wts,
                                              float2* __restrict__ Ut) {
    const int i   = threadIdx.x;   // amplitude index
    const int col = blockIdx.x;    // basis column

    float2 amp = make_float2(i == col ? 1.0f : 0.0f, 0.0f);

    const int ranges[2] = {1, 2};  // l % (NQ-1) + 1 for l = 0,1

    for (int rep = 0; rep < 2; ++rep) {
        for (int l = 0; l < 2; ++l) {
            // --- 6 single-qubit rotations ---
            for (int w = 0; w < NQ; ++w) {
                const float phi = wts[(l * NQ + w) * 3 + 0];
                const float th  = wts[(l * NQ + w) * 3 + 1];
                const float om  = wts[(l * NQ + w) * 3 + 2];
                const float hc = cosf(0.5f * th);
                const float hs = sinf(0.5f * th);
                const float ap = -0.5f * (phi + om);
                const float am = -0.5f * (phi - om);
                const float2 ep = make_float2(cosf(ap), sinf(ap));
                const float2 em = make_float2(cosf(am), sinf(am));
                // U = [[ep*c, -conj(em)*s], [em*s, conj(ep)*c]]
                const float2 U00 = make_float2( ep.x * hc,  ep.y * hc);
                const float2 U01 = make_float2(-em.x * hs,  em.y * hs);
                const float2 U10 = make_float2( em.x * hs,  em.y * hs);
                const float2 U11 = make_float2( ep.x * hc, -ep.y * hc);

                const int p = 5 - w;
                const int bbit = (i >> p) & 1;
                const float px = __shfl_xor(amp.x, 1 << p, 64);
                const float py = __shfl_xor(amp.y, 1 << p, 64);
                const float2 ua = bbit ? U11 : U00;  // coeff of own amp
                const float2 ub = bbit ? U10 : U01;  // coeff of partner amp
                float2 na;
                na.x = ua.x * amp.x - ua.y * amp.y + ub.x * px - ub.y * py;
                na.y = ua.x * amp.y + ua.y * amp.x + ub.x * py + ub.y * px;
                amp = na;
            }
            // --- CNOT ring: control w -> target (w + r) % 6 ---
            const int r = ranges[l];
            for (int w = 0; w < NQ; ++w) {
                const int pc = 5 - w;
                const int pt = 5 - ((w + r) % NQ);
                const int src = i ^ (((i >> pc) & 1) << pt);
                const float nx = __shfl(amp.x, src, 64);
                const float ny = __shfl(amp.y, src, 64);
                amp = make_float2(nx, ny);
            }
        }
    }
    Ut[col * DIM + i] = amp;
}

// ---------------------------------------------------------------------------
// Kernel B: per patch, g = U*feat (complex 64-vec), p_i = |g_i|^2,
// fast WHT over lanes -> z_q = W[1<<(5-q)] / W[0].
// Block = 256 threads (4 waves), handles one (b, oy) row; each wave
// processes 8 ox samples at a time (lane = amplitude index).
// ---------------------------------------------------------------------------
__global__ __launch_bounds__(256) void qconv(const float* __restrict__ x,
                                             const float2* __restrict__ Ut,
                                             float* __restrict__ out) {
    __shared__ float2 sU[DIM * DIM];      // [j][i] = U[i][j], 32 KiB
    __shared__ float4 sF4[4][DIM][2];     // per wave: featT[j][s], 8 KiB

    const int tid  = threadIdx.x;
    const int lane = tid & 63;
    const int wv   = tid >> 6;

    // stage U into LDS (everyone reads it; L2-resident after first block)
    {
        const float4* src = (const float4*)Ut;
        float4* dst = (float4*)sU;
        for (int k = tid; k < DIM * DIM / 2; k += 256) dst[k] = src[k];
    }
    __syncthreads();

    const int bid = blockIdx.x;
    const int b   = bid / OH;
    const int oy  = bid - b * OH;

    // lane -> patch element (c, kh, kw);  feat[j] = x[b, c, oy*2+kh, ox*2+kw]
    const int c  = lane >> 4;
    const int kh = (lane >> 2) & 3;
    const int kw = lane & 3;
    const float* row = x + ((size_t)(b * CIN + c) * HH + (oy * 2 + kh)) * HH + kw;

    const int oxBeg = wv * 16;
    const int oxEnd = min(oxBeg + 16, OH);

    for (int ox0 = oxBeg; ox0 < oxEnd; ox0 += SPT) {
        // ---- stage features for 8 samples: sF[j][s] (clamped ox for tails)
        float f[SPT];
#pragma unroll
        for (int s = 0; s < SPT; ++s) {
            int ox = ox0 + s;
            ox = ox > (OH - 1) ? (OH - 1) : ox;
            f[s] = row[ox * 2];
        }
        sF4[wv][lane][0] = make_float4(f[0], f[1], f[2], f[3]);
        sF4[wv][lane][1] = make_float4(f[4], f[5], f[6], f[7]);

        // ---- complex matvec: lane i accumulates g_i for all 8 samples
        float accx[SPT], accy[SPT];
#pragma unroll
        for (int s = 0; s < SPT; ++s) { accx[s] = 0.0f; accy[s] = 0.0f; }

#pragma unroll 8
        for (int j = 0; j < DIM; ++j) {
            const float2 u  = sU[j * DIM + lane];    // U[i][j]
            const float4 fa = sF4[wv][j][0];         // broadcast
            const float4 fb = sF4[wv][j][1];
            accx[0] += u.x * fa.x;  accy[0] += u.y * fa.x;
            accx[1] += u.x * fa.y;  accy[1] += u.y * fa.y;
            accx[2] += u.x * fa.z;  accy[2] += u.y * fa.z;
            accx[3] += u.x * fa.w;  accy[3] += u.y * fa.w;
            accx[4] += u.x * fb.x;  accy[4] += u.y * fb.x;
            accx[5] += u.x * fb.y;  accy[5] += u.y * fb.y;
            accx[6] += u.x * fb.z;  accy[6] += u.y * fb.z;
            accx[7] += u.x * fb.w;  accy[7] += u.y * fb.w;
        }

        // ---- epilogue: probs -> 6-stage WHT -> z_q = W[1<<(5-q)] / W[0]
        const bool onehot = (lane != 0) && ((lane & (lane - 1)) == 0);
        int q = 0;
        if (onehot) q = 5 - (__ffs(lane) - 1);

#pragma unroll
        for (int s = 0; s < SPT; ++s) {
            float p = accx[s] * accx[s] + accy[s] * accy[s];
#pragma unroll
            for (int k = 0; k < 6; ++k) {
                const int m = 1 << k;
                const float t = __shfl_xor(p, m, 64);
                p = (lane & m) ? (t - p) : (p + t);
            }
            const float w0 = __shfl(p, 0, 64);  // = ||feat||^2 (U unitary)
            const int ox = ox0 + s;
            if (onehot && ox < OH) {
                out[((size_t)(b * NQ + q) * OH + oy) * OH + ox] = p / w0;
            }
        }
    }
}

extern "C" void kernel_launch(void* const* d_in, const int* in_sizes, int n_in,
                              void* d_out, int out_size, void* d_ws, size_t ws_size,
                              hipStream_t stream) {
    const float* x   = (const float*)d_in[0];   // (128, 4, 128, 128) f32
    const float* wts = (const float*)d_in[1];   // (2, 6, 3) f32
    float* out = (float*)d_out;                 // (128, 6, 63, 63) f32
    float2* Ut = (float2*)d_ws;                 // 64*64 float2 = 32 KiB

    build_u<<<64, 64, 0, stream>>>(wts, Ut);
    qconv<<<NB * OH, 256, 0, stream>>>(x, Ut, out);
}

// Round 2
// 114.228 us; speedup vs baseline: 2.0062x; 2.0062x over previous
//
#include <hip/hip_runtime.h>

#define NQ     6
#define DIM    64
#define OH     63
#define HH     128
#define CIN    4
#define NB     128
#define FSTR   72            // LDS row stride (elements), 144B = 16B-aligned

typedef __attribute__((ext_vector_type(8))) short  short8;
typedef __attribute__((ext_vector_type(4))) float  f32x4;

__device__ __forceinline__ unsigned bf16_rne(float f) {
    unsigned u = __builtin_bit_cast(unsigned, f);
    return (u + 0x7fffu + ((u >> 16) & 1u)) >> 16;   // round-nearest-even
}

// ---------------------------------------------------------------------------
// Kernel A: build the 64x64 circuit unitary, Ut[j*64+i] = U[i][j] (re,im).
// ---------------------------------------------------------------------------
__global__ __launch_bounds__(64) void build_u(const float* __restrict__ wts,
                                              float2* __restrict__ Ut) {
    const int i   = threadIdx.x;
    const int col = blockIdx.x;
    float2 amp = make_float2(i == col ? 1.0f : 0.0f, 0.0f);
    const int ranges[2] = {1, 2};

    for (int rep = 0; rep < 2; ++rep) {
        for (int l = 0; l < 2; ++l) {
            for (int w = 0; w < NQ; ++w) {
                const float phi = wts[(l * NQ + w) * 3 + 0];
                const float th  = wts[(l * NQ + w) * 3 + 1];
                const float om  = wts[(l * NQ + w) * 3 + 2];
                const float hc = cosf(0.5f * th);
                const float hs = sinf(0.5f * th);
                const float ap = -0.5f * (phi + om);
                const float am = -0.5f * (phi - om);
                const float2 ep = make_float2(cosf(ap), sinf(ap));
                const float2 em = make_float2(cosf(am), sinf(am));
                const float2 U00 = make_float2( ep.x * hc,  ep.y * hc);
                const float2 U01 = make_float2(-em.x * hs,  em.y * hs);
                const float2 U10 = make_float2( em.x * hs,  em.y * hs);
                const float2 U11 = make_float2( ep.x * hc, -ep.y * hc);
                const int p = 5 - w;
                const int bbit = (i >> p) & 1;
                const float px = __shfl_xor(amp.x, 1 << p, 64);
                const float py = __shfl_xor(amp.y, 1 << p, 64);
                const float2 ua = bbit ? U11 : U00;
                const float2 ub = bbit ? U10 : U01;
                float2 na;
                na.x = ua.x * amp.x - ua.y * amp.y + ub.x * px - ub.y * py;
                na.y = ua.x * amp.y + ua.y * amp.x + ub.x * py + ub.y * px;
                amp = na;
            }
            const int r = ranges[l];
            for (int w = 0; w < NQ; ++w) {
                const int pc = 5 - w;
                const int pt = 5 - ((w + r) % NQ);
                const int src = i ^ (((i >> pc) & 1) << pt);
                const float nx = __shfl(amp.x, src, 64);
                const float ny = __shfl(amp.y, src, 64);
                amp = make_float2(nx, ny);
            }
        }
    }
    Ut[col * DIM + i] = amp;
}

// ---------------------------------------------------------------------------
// Kernel B: pack W = [Re U; Im U] (128x64) into per-lane MFMA A-fragments,
// split hi/lo bf16.  frag f (0..15 = Whi, 16..31 = Wlo): mt = (f&15)>>1,
// t = f&1; lane l holds A[m = mt*16 + (l&15)][k = t*32 + (l>>4)*8 + j].
// Stored flat: wfrag[(f*64 + l)*8 + j]  (one int4 per lane-frag).
// ---------------------------------------------------------------------------
__global__ __launch_bounds__(64) void wprep(const float2* __restrict__ Ut,
                                            short* __restrict__ wfrag) {
    const int f = blockIdx.x;       // 0..31
    const int l = threadIdx.x;
    const int lo = f >> 4;
    const int mt = (f & 15) >> 1;
    const int t  = f & 1;
    const int m  = mt * 16 + (l & 15);
    short8 v;
#pragma unroll
    for (int j = 0; j < 8; ++j) {
        const int k = t * 32 + (l >> 4) * 8 + j;
        const float2 u = Ut[k * DIM + (m & 63)];
        const float val = (m < 64) ? u.x : u.y;
        const unsigned h = bf16_rne(val);
        if (lo == 0) {
            v[j] = (short)h;
        } else {
            const float fh = __builtin_bit_cast(float, h << 16);
            v[j] = (short)bf16_rne(val - fh);
        }
    }
    ((int4*)wfrag)[f * 64 + l] = __builtin_bit_cast(int4, v);
}

// ---------------------------------------------------------------------------
// Kernel C: main. 1 wave per (b,oy) row; 4 chunks of 16 samples (ox).
//  G = (Whi+Wlo)·F  via mfma 16x16x32 bf16 (8 m-tiles, K=64)
//  P[i][n] = G_re^2 + G_im^2 ;  Z = S·P via 2 more MFMAs (S = ±1 signs)
//  z_q = Z[q][n] / Z[6][n]   (row 6 of S is all-ones -> norm = ||f||^2)
// ---------------------------------------------------------------------------
__global__ __launch_bounds__(256, 2) void qconv_mfma(const float* __restrict__ x,
                                                     const short* __restrict__ wfrag,
                                                     float* __restrict__ out) {
    __shared__ __align__(16) short sF[4][16 * FSTR];
    __shared__ __align__(16) short sP[4][16 * FSTR];

    const int tid  = threadIdx.x;
    const int lane = tid & 63;
    const int wv   = tid >> 6;
    const int n    = lane & 15;     // sample within chunk
    const int qq   = lane >> 4;     // quad

    const int row = blockIdx.x * 4 + wv;   // 0..8063
    const int b   = row / OH;
    const int oy  = row - b * OH;

    // ---- preload W fragments (32 coalesced int4 loads, L2-resident) ----
    short8 whi[8][2], wlo[8][2];
    {
        const int4* wp = (const int4*)wfrag;
#pragma unroll
        for (int mt = 0; mt < 8; ++mt)
#pragma unroll
            for (int t = 0; t < 2; ++t) {
                const int f = mt * 2 + t;
                whi[mt][t] = __builtin_bit_cast(short8, wp[f * 64 + lane]);
                wlo[mt][t] = __builtin_bit_cast(short8, wp[(16 + f) * 64 + lane]);
            }
    }

    // ---- S fragments (A-operand, rows q: 0..5 signs, 6 ones, 7..15 zero) ----
    short8 sfr[2];
#pragma unroll
    for (int t = 0; t < 2; ++t) {
        short8 v;
#pragma unroll
        for (int j = 0; j < 8; ++j) {
            const int i = t * 32 + qq * 8 + j;
            unsigned short s;
            if (n < 6)       s = ((i >> (5 - n)) & 1) ? 0xBF80 : 0x3F80;
            else if (n == 6) s = 0x3F80;
            else             s = 0;
            v[j] = (short)s;
        }
        sfr[t] = v;
    }

    short* myF = sF[wv];
    short* myP = sP[wv];

    // ---- per-lane staging bases: lane handles n, k-pairs kp = it*4+qq ----
    const float* xb = x + (size_t)b * CIN * HH * HH;
    const float* bptr[8];
#pragma unroll
    for (int it = 0; it < 8; ++it) {
        const int kp  = it * 4 + qq;          // 0..31
        const int c   = kp >> 3;
        const int kh  = (kp >> 1) & 3;
        const int kwh = kp & 1;
        bptr[it] = xb + (c * HH + 2 * oy + kh) * HH + 2 * kwh;
    }

    // prologue: loads for chunk 0
    float2 fv[8];
#pragma unroll
    for (int it = 0; it < 8; ++it) fv[it] = *(const float2*)(bptr[it] + 2 * n);

    for (int ch = 0; ch < 4; ++ch) {
        // ---- write current features to LDS (bf16 RNE, packed pairs) ----
#pragma unroll
        for (int it = 0; it < 8; ++it) {
            const unsigned lo = bf16_rne(fv[it].x);
            const unsigned hi = bf16_rne(fv[it].y);
            ((unsigned*)myF)[n * (FSTR / 2) + it * 4 + qq] = lo | (hi << 16);
        }
        // ---- prefetch next chunk (clamped; dead for ch==3) ----
        {
            const int oxe = min(ch * 16 + 16 + n, OH - 1);
#pragma unroll
            for (int it = 0; it < 8; ++it)
                fv[it] = *(const float2*)(bptr[it] + 2 * oxe);
        }

        // ---- B fragments from LDS ----
        const short8 b0 = *(const short8*)(myF + n * FSTR + qq * 8);
        const short8 b1 = *(const short8*)(myF + n * FSTR + 32 + qq * 8);

        // ---- first GEMM: G = (Whi + Wlo) · F ----
        f32x4 acc[8];
#pragma unroll
        for (int mt = 0; mt < 8; ++mt) acc[mt] = (f32x4){0.f, 0.f, 0.f, 0.f};
#pragma unroll
        for (int mt = 0; mt < 8; ++mt) {
            acc[mt] = __builtin_amdgcn_mfma_f32_16x16x32_bf16(whi[mt][0], b0, acc[mt], 0, 0, 0);
            acc[mt] = __builtin_amdgcn_mfma_f32_16x16x32_bf16(whi[mt][1], b1, acc[mt], 0, 0, 0);
            acc[mt] = __builtin_amdgcn_mfma_f32_16x16x32_bf16(wlo[mt][0], b0, acc[mt], 0, 0, 0);
            acc[mt] = __builtin_amdgcn_mfma_f32_16x16x32_bf16(wlo[mt][1], b1, acc[mt], 0, 0, 0);
        }

        // ---- P = Gre^2 + Gim^2 -> bf16 (truncate) -> LDS ----
#pragma unroll
        for (int mt = 0; mt < 4; ++mt) {
            const float p0 = acc[mt][0] * acc[mt][0] + acc[mt + 4][0] * acc[mt + 4][0];
            const float p1 = acc[mt][1] * acc[mt][1] + acc[mt + 4][1] * acc[mt + 4][1];
            const float p2 = acc[mt][2] * acc[mt][2] + acc[mt + 4][2] * acc[mt + 4][2];
            const float p3 = acc[mt][3] * acc[mt][3] + acc[mt + 4][3] * acc[mt + 4][3];
            const unsigned w0 = (__builtin_bit_cast(unsigned, p0) >> 16) |
                                (__builtin_bit_cast(unsigned, p1) & 0xFFFF0000u);
            const unsigned w1 = (__builtin_bit_cast(unsigned, p2) >> 16) |
                                (__builtin_bit_cast(unsigned, p3) & 0xFFFF0000u);
            *((uint2*)(((unsigned*)myP) + n * (FSTR / 2) + mt * 8 + qq * 2)) =
                make_uint2(w0, w1);
        }

        // ---- second GEMM: Z = S · P ----
        const short8 p0f = *(const short8*)(myP + n * FSTR + qq * 8);
        const short8 p1f = *(const short8*)(myP + n * FSTR + 32 + qq * 8);
        f32x4 c2 = (f32x4){0.f, 0.f, 0.f, 0.f};
        c2 = __builtin_amdgcn_mfma_f32_16x16x32_bf16(sfr[0], p0f, c2, 0, 0, 0);
        c2 = __builtin_amdgcn_mfma_f32_16x16x32_bf16(sfr[1], p1f, c2, 0, 0, 0);

        // ---- normalize + store: row q = qq*4 + reg; norm = row 6 ----
        const float norm = __shfl(c2[2], 16 + n, 64);
        const float inv  = 1.0f / norm;
        const int ox = ch * 16 + n;
        if (ox < OH) {
            float* ob = out + ((size_t)b * NQ * OH + oy) * OH + ox;
            if (qq == 0) {
#pragma unroll
                for (int r = 0; r < 4; ++r) ob[(size_t)r * (OH * OH)] = c2[r] * inv;
            } else if (qq == 1) {
                ob[(size_t)4 * (OH * OH)] = c2[0] * inv;
                ob[(size_t)5 * (OH * OH)] = c2[1] * inv;
            }
        }
    }
}

extern "C" void kernel_launch(void* const* d_in, const int* in_sizes, int n_in,
                              void* d_out, int out_size, void* d_ws, size_t ws_size,
                              hipStream_t stream) {
    const float* x   = (const float*)d_in[0];   // (128, 4, 128, 128) f32
    const float* wts = (const float*)d_in[1];   // (2, 6, 3) f32
    float* out = (float*)d_out;                 // (128, 6, 63, 63) f32

    float2* Ut    = (float2*)d_ws;                          // 32 KiB
    short*  wfrag = (short*)((char*)d_ws + 64 * 1024);      // 32 KiB

    build_u<<<64, 64, 0, stream>>>(wts, Ut);
    wprep<<<32, 64, 0, stream>>>(Ut, wfrag);
    qconv_mfma<<<(NB * OH) / 4, 256, 0, stream>>>(x, wfrag, out);
}